// Round 7
// baseline (867.539 us; speedup 1.0000x reference)
//
#include <hip/hip_runtime.h>
#include <stdint.h>

// GenerativeWorldModel: B=2048,T=50,N=23,F=4,H=64,FUT=10. All I/O fp32.
// 1 wave = 1 batch, 512 thr/block (8 waves), 256 blocks, no barriers in loop.
// All GEMMs transposed (D[row=feature][col=node]); h recurrence in registers.
// R7 vs R3..R6: the 425MB scratch resisted launch-bounds (R4), scalar
//   renaming (R5), waves_per_eu + LDS padding (R5/R6) -- VGPR pinned at 128
//   through all knobs => structural scratch, not pressure spill. Remaining
//   structural delta vs R0 (zero scratch): the big multi-call LAMBDAS
//   (spath/gru/act/load_adj). If clang outlines a lambda, every by-ref
//   capture (bS/bH/hC/adj regs) becomes address-taken -> capture frame in
//   scratch (~55B/lane/iter = the 430MB). Fix: textual macros (cannot be a
//   call), adj prefetch in 4 named f32x4 vector regs, zero local arrays in
//   the loop. Only R0-proven tiny `mm` lambda + forceinline cvt_tile remain.
// R3 vs baseline (343us/dispatch):
//  1) cvt_tile via two-arg v_permlane32_swap (4 VALU ops replace 4
//     ds_bpermute + cndmasks).
//  2) adj LDS staging (div-23 transpose + ds round trip) -> direct per-row
//     global loads into registers; bA frags packed straight from regs.
//  3) software pipeline: S-path(t+1) (x/adj -> E -> S) is h-independent, so
//     it runs between GRU-MFMA(t) and the trans-heavy activations of t.

typedef _Float16 f16;
typedef f16   f16x2  __attribute__((ext_vector_type(2)));
typedef f16   f16x8  __attribute__((ext_vector_type(8)));
typedef float f32x4n __attribute__((ext_vector_type(4)));
typedef float f32x16 __attribute__((ext_vector_type(16)));
typedef int   i32x2  __attribute__((ext_vector_type(2)));
typedef float f32x4u __attribute__((ext_vector_type(4), aligned(4)));

#define WBYTES 69632            // 68 weight frags * 1024 B
#define PW 512                  // per-wave: xL f32[128]
#define SMEM_BYTES 98304        // >81920 -> 1 block/CU (grid is 1 block/CU anyway)

static __device__ __forceinline__ unsigned pk2(float a, float b) {
    f16x2 h; h[0] = (f16)a; h[1] = (f16)b;
    return __builtin_bit_cast(unsigned, h);
}
static __device__ __forceinline__ f16x8 mkfrag(unsigned a, unsigned b, unsigned c, unsigned d) {
    uint4 u = make_uint4(a, b, c, d);
    return __builtin_bit_cast(f16x8, u);
}
// v_permlane32_swap(a,b): exchanges hi-half(a) with lo-half(b).
// r0 = {a.lo | b.lo-values in hi lanes}, r1 = {a.hi-values in lo lanes | b.hi}
static __device__ __forceinline__ void pswap2(unsigned a, unsigned b,
                                              unsigned& r0, unsigned& r1) {
    auto r = __builtin_amdgcn_permlane32_swap((int)a, (int)b, false, false);
    i32x2 v = __builtin_bit_cast(i32x2, r);
    r0 = (unsigned)v[0]; r1 = (unsigned)v[1];
}
// hi-dup of x: every lane gets x from lane 32|(l&31)
static __device__ __forceinline__ unsigned dup_hi(unsigned x) {
    unsigned r0, r1; pswap2(x, x, r0, r1); return r1;
}

static __device__ __forceinline__ float sigm(float x) {
    return __builtin_amdgcn_rcpf(1.f + __expf(-x));
}
static __device__ __forceinline__ float tanhp(float x) {
    return 1.f - 2.f * __builtin_amdgcn_rcpf(1.f + __expf(2.f * x));
}
// C-layout f32x16 tile (row=(i&3)+8*(i>>2)+4*hf, col=l31) -> two B-frags
// fe = tile rows 0..15, fo = rows 16..31.  Lane mapping:
//   fe(lo lanes) = (lo.u0, lo.u1, hi.u0, hi.u1)   [rows 0-3, 4-7]
//   fe(hi lanes) = (lo.u2, lo.u3, hi.u2, hi.u3)   [rows 8-11, 12-15]
// pswap2(u0,u2) yields exactly (word0, word2); pswap2(u1,u3) -> (word1, word3).
static __device__ __forceinline__ void cvt_tile(const f32x16& v, f16x8& fe, f16x8& fo) {
    unsigned e0, e1, e2, e3, o0, o1, o2, o3;
    pswap2(pk2(v[0], v[1]),   pk2(v[4], v[5]),   e0, e2);
    pswap2(pk2(v[2], v[3]),   pk2(v[6], v[7]),   e1, e3);
    pswap2(pk2(v[8], v[9]),   pk2(v[12], v[13]), o0, o2);
    pswap2(pk2(v[10], v[11]), pk2(v[14], v[15]), o1, o3);
    fe = mkfrag(e0, e1, e2, e3);
    fo = mkfrag(o0, o1, o2, o3);
}

// ---- phase macros: textual inlining, no call/capture frame possible ----
#define LOAD_ADJ(t) do { \
    ca = z4; cb = z4; cc = z4; cd = z4; \
    if (l31 < 23) { \
        const float* ar_ = ag + (t) * 529 + l31 * 23 + 8 * hf; \
        ca = *(const f32x4u*)ar_; \
        cb = *(const f32x4u*)(ar_ + 4); \
        if (hf == 0) { \
            cc = *(const f32x4u*)(ar_ + 16); \
            cd[0] = ar_[20]; cd[1] = ar_[21]; cd[2] = ar_[22]; \
        } \
    } \
} while (0)

#define PACK_ADJ() do { \
    bA0 = mkfrag(pk2(ca[0],ca[1]), pk2(ca[2],ca[3]), pk2(cb[0],cb[1]), pk2(cb[2],cb[3])); \
    bA1 = mkfrag(pk2(cc[0],cc[1]), pk2(cc[2],cc[3]), pk2(cd[0],cd[1]), pk2(cd[2],cd[3])); \
} while (0)

#define LOAD_X(t) do { \
    if (lane < 23) pfx = *(const f32x4n*)(xg + (t) * 92 + 4 * lane); \
} while (0)

#define STAGE_X() do { \
    if (lane < 23) *(f32x4n*)(xL + 4 * lane) = pfx; \
} while (0)

#define SPATH(O0, O1, O2, O3) do { \
    f16x8 aX0_, aX1_; \
    { \
        float w00_, w01_, w02_, w03_, w04_, w05_, w06_, w07_; \
        float w10_, w11_, w12_, w13_, w14_, w15_, w16_, w17_; \
        const int f_ = l31 & 3; \
        const float fill_ = (l31 == 4) ? 1.f : 0.f; \
        const int base0_ = (8 * hf) * 4 + f_, base1_ = (16 + 8 * hf) * 4 + f_; \
        w00_ = (l31 < 4) ? xL[base0_ +  0] : fill_; \
        w01_ = (l31 < 4) ? xL[base0_ +  4] : fill_; \
        w02_ = (l31 < 4) ? xL[base0_ +  8] : fill_; \
        w03_ = (l31 < 4) ? xL[base0_ + 12] : fill_; \
        w04_ = (l31 < 4) ? xL[base0_ + 16] : fill_; \
        w05_ = (l31 < 4) ? xL[base0_ + 20] : fill_; \
        w06_ = (l31 < 4) ? xL[base0_ + 24] : fill_; \
        w07_ = (l31 < 4) ? xL[base0_ + 28] : fill_; \
        w10_ = (l31 < 4) ? xL[base1_ +  0] : fill_; \
        w11_ = (l31 < 4) ? xL[base1_ +  4] : fill_; \
        w12_ = (l31 < 4) ? xL[base1_ +  8] : fill_; \
        w13_ = (l31 < 4) ? xL[base1_ + 12] : fill_; \
        w14_ = (l31 < 4) ? xL[base1_ + 16] : fill_; \
        w15_ = (l31 < 4) ? xL[base1_ + 20] : fill_; \
        w16_ = (l31 < 4) ? xL[base1_ + 24] : fill_; \
        w17_ = (l31 < 4) ? xL[base1_ + 28] : fill_; \
        aX0_ = mkfrag(pk2(w00_,w01_), pk2(w02_,w03_), pk2(w04_,w05_), pk2(w06_,w07_)); \
        aX1_ = mkfrag(pk2(w10_,w11_), pk2(w12_,w13_), pk2(w14_,w15_), pk2(w16_,w17_)); \
    } \
    f32x16 accE_ = z16; \
    accE_ = __builtin_amdgcn_mfma_f32_32x32x16_f16(aX0_, bA0, accE_, 0, 0, 0); \
    accE_ = __builtin_amdgcn_mfma_f32_32x32x16_f16(aX1_, bA1, accE_, 0, 0, 0); \
    const unsigned p01_ = pk2(accE_[0], accE_[1]), p23_ = pk2(accE_[2], accE_[3]); \
    const unsigned p4_  = dup_hi(pk2(accE_[0], 0.f)); \
    const f16x8 bE_ = hf ? mkfrag(0u, 0u, 0u, 0u) : mkfrag(p01_, p23_, p4_, 0u); \
    f32x16 s0_ = z16, s1_ = z16; \
    s0_ = __builtin_amdgcn_mfma_f32_32x32x16_f16(aWg0, bE_, s0_, 0, 0, 0); \
    s1_ = __builtin_amdgcn_mfma_f32_32x32x16_f16(aWg1, bE_, s1_, 0, 0, 0); \
    _Pragma("unroll") \
    for (int i_ = 0; i_ < 16; ++i_) { s0_[i_] = fmaxf(s0_[i_], 0.f); s1_[i_] = fmaxf(s1_[i_], 0.f); } \
    cvt_tile(s0_, O0, O1); \
    cvt_tile(s1_, O2, O3); \
} while (0)

// fi = (side*6+tau)*5+kt; side0 uses BS, side1 uses BH; tau: R=hn, Z=2+hn, N=4+hn
#define GQ(kt, BS, BH, AR, AZ, ANI, ANH, hn) \
    AR  = mm(AR,  ((hn)     ) * 5 + (kt), BS); \
    AR  = mm(AR,  ( 6 + (hn)) * 5 + (kt), BH); \
    AZ  = mm(AZ,  ( 2 + (hn)) * 5 + (kt), BS); \
    AZ  = mm(AZ,  ( 8 + (hn)) * 5 + (kt), BH); \
    ANI = mm(ANI, ( 4 + (hn)) * 5 + (kt), BS); \
    ANH = mm(ANH, (10 + (hn)) * 5 + (kt), BH);

#define GRU(hn, AR, AZ, ANI, ANH) do { \
    AR = z16; AZ = z16; ANI = z16; ANH = z16; \
    GQ(0, bS0, bH0, AR, AZ, ANI, ANH, hn) \
    GQ(1, bS1, bH1, AR, AZ, ANI, ANH, hn) \
    GQ(2, bS2, bH2, AR, AZ, ANI, ANH, hn) \
    GQ(3, bS3, bH3, AR, AZ, ANI, ANH, hn) \
    AR  = mm(AR,  ((hn)     ) * 5 + 4, bC); \
    AZ  = mm(AZ,  ( 2 + (hn)) * 5 + 4, bC); \
    ANI = mm(ANI, ( 4 + (hn)) * 5 + 4, bC); \
    ANH = mm(ANH, (10 + (hn)) * 5 + 4, bC); \
} while (0)

#define ACT(HV, AR, AZ, ANI, ANH, NBE, NBO) do { \
    _Pragma("unroll") \
    for (int i_ = 0; i_ < 16; ++i_) { \
        const float r_ = sigm(AR[i_]); \
        const float z_ = sigm(AZ[i_]); \
        const float n_ = tanhp(ANI[i_] + r_ * ANH[i_]); \
        HV[i_] = n_ + z_ * (HV[i_] - n_); \
    } \
    cvt_tile(HV, NBE, NBO); \
} while (0)

__global__ __launch_bounds__(512)
__attribute__((amdgpu_waves_per_eu(2, 2)))
void gwm_kernel(
    const float* __restrict__ xseq, const float* __restrict__ adjseq,
    const float* __restrict__ Wg,  const float* __restrict__ bg,
    const float* __restrict__ Wih, const float* __restrict__ Whh,
    const float* __restrict__ bih, const float* __restrict__ bhh,
    const float* __restrict__ Wd1, const float* __restrict__ bd1,
    const float* __restrict__ Wd2, const float* __restrict__ bd2,
    float* __restrict__ out)
{
    extern __shared__ char smem[];
    const int tid  = threadIdx.x;
    const int lane = tid & 63;
    const int wv   = tid >> 6;
    const int l31  = lane & 31;
    const int hf   = lane >> 5;

    // ---- pack weights (A-frags, fp16) + bias columns into LDS (once) ----
    for (int idx = tid; idx < 68 * 64; idx += 512) {
        const int fi = idx >> 6, l = idx & 63, ln = l & 31, lh = l >> 5;
        float v[8];
        #pragma unroll
        for (int j = 0; j < 8; ++j) v[j] = 0.f;
        if (fi < 60) {
            const int grp = fi / 5, kt = fi - grp * 5;
            const int side = grp / 6, tau = grp - side * 6;
            const float* W = side ? Whh : Wih;
            const int row = tau * 32 + ln;
            if (kt < 4) {
                const float* s = W + row * 64 + kt * 16 + lh * 8;
                #pragma unroll
                for (int j = 0; j < 8; ++j) v[j] = s[j];
            } else if (lh == 0) {
                if (side == 0) v[0] = bih[row] + (tau < 4 ? bhh[row] : 0.f);
                else           v[0] = (tau < 4) ? 0.f : bhh[row];
            }
        } else if (fi < 65) {
            const int kt = fi - 60;
            if (kt < 4) {
                const float* s = Wd1 + ln * 64 + kt * 16 + lh * 8;
                #pragma unroll
                for (int j = 0; j < 8; ++j) v[j] = s[j];
            } else if (lh == 0) v[0] = bd1[ln];
        } else {
            const int kt = fi - 65;
            if (kt < 2) {
                if (ln < 4) {
                    const float* s = Wd2 + ln * 32 + kt * 16 + lh * 8;
                    #pragma unroll
                    for (int j = 0; j < 8; ++j) v[j] = s[j];
                }
            } else if (lh == 0 && ln < 4) v[0] = bd2[ln];
        }
        f16x8 h8;
        #pragma unroll
        for (int j = 0; j < 8; ++j) h8[j] = (f16)v[j];
        *(f16x8*)(smem + fi * 1024 + l * 16) = h8;
    }

    float* xL = (float*)(smem + WBYTES + wv * PW);   // f32[128] (92 real + zero pad)
    xL[lane] = 0.f; xL[lane + 64] = 0.f;
    __syncthreads();   // weight frags visible

    // ---- per-lane constants ----
    const f16x8 bC = (hf == 0) ? mkfrag(pk2(1.f, 0.f), 0u, 0u, 0u)
                               : mkfrag(0u, 0u, 0u, 0u);
    f16x8 aWg0, aWg1;
    {
        const int c0 = l31, c1 = 32 + l31;
        aWg0 = hf ? mkfrag(0u,0u,0u,0u)
                  : mkfrag(pk2(Wg[c0*4], Wg[c0*4+1]), pk2(Wg[c0*4+2], Wg[c0*4+3]),
                           pk2(bg[c0], 0.f), 0u);
        aWg1 = hf ? mkfrag(0u,0u,0u,0u)
                  : mkfrag(pk2(Wg[c1*4], Wg[c1*4+1]), pk2(Wg[c1*4+2], Wg[c1*4+3]),
                           pk2(bg[c1], 0.f), 0u);
    }

    const int b = blockIdx.x * 8 + wv;
    const float* xg = xseq   + (size_t)b * (50 * 92);
    const float* ag = adjseq + (size_t)b * (50 * 529);
    float* outb = out + (size_t)b * 920;

    // ---- recurrent state: named vector registers only, zero local arrays ----
    f32x16 hC0, hC1;
    f16x8  bH0, bH1, bH2, bH3;
    f16x8  bS0, bS1, bS2, bS3;
    f16x8  bA0, bA1;              // adj^T B-frags for the t in the S-path
    f32x4u ca, cb, cc, cd;        // adj row prefetch (4 vector regs)
    f32x4n pfx;
    #pragma unroll
    for (int i = 0; i < 16; ++i) { hC0[i] = 0.f; hC1[i] = 0.f; }
    bH0 = bH1 = bH2 = bH3 = mkfrag(0u, 0u, 0u, 0u);

    f32x16 z16;
    #pragma unroll
    for (int i = 0; i < 16; ++i) z16[i] = 0.f;
    f32x4u z4; z4[0] = z4[1] = z4[2] = z4[3] = 0.f;

    auto mm = [&](f32x16 acc, int fi, f16x8 bfr) -> f32x16 {
        const f16x8 aW = *(const f16x8*)(smem + fi * 1024 + lane * 16);
        return __builtin_amdgcn_mfma_f32_32x32x16_f16(aW, bfr, acc, 0, 0, 0);
    };

    // ---- prologue: S(0) + prefetch t=1 ----
    LOAD_X(0); STAGE_X();
    LOAD_ADJ(0); PACK_ADJ();
    LOAD_X(1);
    SPATH(bS0, bS1, bS2, bS3);
    LOAD_ADJ(1);

    // ---- history, pipelined: iter t does GRU(t) and S-path(t+1) ----
    for (int t = 0; t < 49; ++t) {
        f32x16 aR0, aZ0, aNi0, aNh0, aR1, aZ1, aNi1, aNh1;
        f16x8 nb0, nb1, nb2, nb3, nS0, nS1, nS2, nS3;
        GRU(0, aR0, aZ0, aNi0, aNh0);
        STAGE_X();                          // xL <- x(t+1)
        ACT(hC0, aR0, aZ0, aNi0, aNh0, nb0, nb1);
        PACK_ADJ();                         // bA <- adj(t+1)
        const int tp = (t + 2 < 50) ? t + 2 : 49;   // clamp: branch-free body
        LOAD_ADJ(tp); LOAD_X(tp);           // regs <- adj(t+2), pfx <- x(t+2)
        SPATH(nS0, nS1, nS2, nS3);          // S(t+1), overlaps GRU/act
        GRU(1, aR1, aZ1, aNi1, aNh1);
        ACT(hC1, aR1, aZ1, aNi1, aNh1, nb2, nb3);
        bH0 = nb0; bH1 = nb1; bH2 = nb2; bH3 = nb3;
        bS0 = nS0; bS1 = nS1; bS2 = nS2; bS3 = nS3;
    }

    // ---- t = 49: last history GRU (bS = S(49), bA = adj(49), xL = x(49)) ----
    {
        f32x16 aR0, aZ0, aNi0, aNh0, aR1, aZ1, aNi1, aNh1;
        f16x8 nb0, nb1, nb2, nb3;
        GRU(0, aR0, aZ0, aNi0, aNh0);
        ACT(hC0, aR0, aZ0, aNi0, aNh0, nb0, nb1);
        GRU(1, aR1, aZ1, aNi1, aNh1);
        ACT(hC1, aR1, aZ1, aNi1, aNh1, nb2, nb3);
        bH0 = nb0; bH1 = nb1; bH2 = nb2; bH3 = nb3;
    }

    // ---- future: serial (decode(t) feeds x(t+1)); adj frags fixed at t=49 ----
    for (int fs = 0; fs < 10; ++fs) {
        SPATH(bS0, bS1, bS2, bS3);
        f32x16 aR0, aZ0, aNi0, aNh0, aR1, aZ1, aNi1, aNh1;
        f16x8 nb0, nb1, nb2, nb3;
        GRU(0, aR0, aZ0, aNi0, aNh0);
        ACT(hC0, aR0, aZ0, aNi0, aNh0, nb0, nb1);
        GRU(1, aR1, aZ1, aNi1, aNh1);
        ACT(hC1, aR1, aZ1, aNi1, aNh1, nb2, nb3);
        bH0 = nb0; bH1 = nb1; bH2 = nb2; bH3 = nb3;

        f32x16 d1 = z16;
        d1 = mm(d1, 60, bH0);
        d1 = mm(d1, 61, bH1);
        d1 = mm(d1, 62, bH2);
        d1 = mm(d1, 63, bH3);
        d1 = mm(d1, 64, bC);
        #pragma unroll
        for (int i = 0; i < 16; ++i) d1[i] = fmaxf(d1[i], 0.f);
        f16x8 bD0, bD1;
        cvt_tile(d1, bD0, bD1);
        f32x16 d2 = z16;
        d2 = mm(d2, 65, bD0);
        d2 = mm(d2, 66, bD1);
        d2 = mm(d2, 67, bC);
        if (hf == 0 && l31 < 23) {
            f32x4n o;
            o[0] = d2[0]; o[1] = d2[1]; o[2] = d2[2]; o[3] = d2[3];
            *(f32x4n*)(outb + fs * 92 + l31 * 4) = o;
            *(f32x4n*)(xL + l31 * 4) = o;     // feeds next step's X^
        }
    }
}

extern "C" void kernel_launch(void* const* d_in, const int* in_sizes, int n_in,
                              void* d_out, int out_size, void* d_ws, size_t ws_size,
                              hipStream_t stream) {
    (void)in_sizes; (void)n_in; (void)d_ws; (void)ws_size; (void)out_size;
    hipFuncSetAttribute((const void*)gwm_kernel,
                        hipFuncAttributeMaxDynamicSharedMemorySize, SMEM_BYTES);
    gwm_kernel<<<dim3(256), dim3(512), SMEM_BYTES, stream>>>(
        (const float*)d_in[0], (const float*)d_in[1], (const float*)d_in[2],
        (const float*)d_in[3], (const float*)d_in[4], (const float*)d_in[5],
        (const float*)d_in[6], (const float*)d_in[7], (const float*)d_in[8],
        (const float*)d_in[9], (const float*)d_in[10], (const float*)d_in[11],
        (float*)d_out);
}